// Round 9
// baseline (461.508 us; speedup 1.0000x reference)
//
#include <hip/hip_runtime.h>
#include <hip/hip_bf16.h>
#include <math.h>

#define NN 50000
#define EE 800000
#define NPG 5000

typedef short bf16x8 __attribute__((ext_vector_type(8)));
typedef float f32x4 __attribute__((ext_vector_type(4)));
typedef float f32x2 __attribute__((ext_vector_type(2)));

#if __has_builtin(__builtin_amdgcn_cvt_pk_f32_fp8) && __has_builtin(__builtin_amdgcn_cvt_pk_fp8_f32)
#define HWFP8 1
#else
#define HWFP8 0
#endif

__device__ __forceinline__ float gelu_exact(float v) {
    return 0.5f * v * (1.0f + erff(v * 0.70710678118654752440f));
}

__device__ __forceinline__ ushort f2b(float f) {
    union { float f; uint u; } v; v.f = f;
    uint r = (v.u + 0x7fffu + ((v.u >> 16) & 1)) >> 16;
    return (ushort)r;
}
__device__ __forceinline__ uint pack2(float a, float b) {
    return (uint)f2b(a) | ((uint)f2b(b) << 16);
}
__device__ __forceinline__ float blo(uint u) {
    union { uint u; float f; } v; v.u = u << 16; return v.f;
}
__device__ __forceinline__ float bhi(uint u) {
    union { uint u; float f; } v; v.u = u & 0xffff0000u; return v.f;
}
__device__ __forceinline__ void unpack8(uint4 u, float* f) {
    f[0] = blo(u.x); f[1] = bhi(u.x); f[2] = blo(u.y); f[3] = bhi(u.y);
    f[4] = blo(u.z); f[5] = bhi(u.z); f[6] = blo(u.w); f[7] = bhi(u.w);
}
__device__ __forceinline__ void load16f(const float* p, float* out) {
#pragma unroll
    for (int i = 0; i < 4; ++i) {
        float4 t = *(const float4*)(p + 4 * i);
        out[4 * i] = t.x; out[4 * i + 1] = t.y; out[4 * i + 2] = t.z; out[4 * i + 3] = t.w;
    }
}

// ---- software e4m3fn (fallback; hw path uses v_cvt_pk_* so enc/dec always match) ----
__device__ __forceinline__ uchar f2fp8_sw(float f) {
    uint u = __float_as_uint(f);
    uint sign = (u >> 24) & 0x80u;
    uint absu = u & 0x7fffffffu;
    if (absu >= 0x43e00000u) return (uchar)(sign | 0x7eu);     // sat to 448
    int e32 = (int)(absu >> 23);
    if (e32 < 121) {                                            // subnormal: m * 2^-9
        float af = __uint_as_float(absu);
        uint m = (uint)__float2int_rn(af * 512.f);
        return (uchar)(sign | m);
    }
    uint mant = absu & 0x7fffffu;
    uint keep = mant >> 20;
    uint rest = mant & 0xfffffu;
    uint rnd = (rest > 0x80000u || (rest == 0x80000u && (keep & 1u))) ? 1u : 0u;
    uint code = (((uint)(e32 - 120) << 3) | keep) + rnd;
    if (code > 0x7eu) code = 0x7eu;
    return (uchar)(sign | code);
}
__device__ __forceinline__ float fp82f_sw(uint b) {
    uint em = b & 0x7fu;
    uint s = (b & 0x80u) << 24;
    float norm = __uint_as_float(s | (((em >> 3) + 120u) << 23) | ((em & 7u) << 20));
    float sub = __uint_as_float(s | 0x3F800000u) * (float)(int)em * 0.001953125f;
    return (em >= 8u) ? norm : sub;
}
__device__ __forceinline__ uchar enc1(float v) {
#if HWFP8
    return (uchar)(__builtin_amdgcn_cvt_pk_fp8_f32(v, v, 0, false) & 0xff);
#else
    return f2fp8_sw(v);
#endif
}
__device__ __forceinline__ void dec16(uint4 u, float* f) {
#pragma unroll
    for (int i = 0; i < 4; ++i) {
        uint w = (&u.x)[i];
#if HWFP8
        f32x2 lo = __builtin_amdgcn_cvt_pk_f32_fp8((int)w, false);
        f32x2 hi = __builtin_amdgcn_cvt_pk_f32_fp8((int)w, true);
        f[4 * i] = lo.x; f[4 * i + 1] = lo.y; f[4 * i + 2] = hi.x; f[4 * i + 3] = hi.y;
#else
        f[4 * i]     = fp82f_sw(w & 0xffu);
        f[4 * i + 1] = fp82f_sw((w >> 8) & 0xffu);
        f[4 * i + 2] = fp82f_sw((w >> 16) & 0xffu);
        f[4 * i + 3] = fp82f_sw((w >> 24) & 0xffu);
#endif
    }
}

// ================= K1: colstats(0-1023) | hist(1024-4148) | convert(4149-4660) =================
__global__ __launch_bounds__(256) void head1_kernel(const float* __restrict__ x,
        float* __restrict__ sums, const int* __restrict__ dst, int* __restrict__ counts,
        const float* __restrict__ Ws0, const float* __restrict__ Wd0,
        const float* __restrict__ Ws1, const float* __restrict__ Wd1,
        const float* __restrict__ Wo1, const float* __restrict__ Wo2,
        ushort* __restrict__ Wt0, ushort* __restrict__ Wt1,
        ushort* __restrict__ Wo1t, ushort* __restrict__ Wo2t) {
    int bid = blockIdx.x;
    int tid = threadIdx.x;
    if (bid < 1024) {
        int col4 = (tid & 31) * 4;
        int rowgrp = tid >> 5;
        float s0 = 0.f, s1 = 0.f, s2 = 0.f, s3 = 0.f;
        float q0 = 0.f, q1 = 0.f, q2 = 0.f, q3 = 0.f;
        for (int r = bid * 8 + rowgrp; r < NN; r += 8192) {
            float4 v = *(const float4*)(x + (size_t)r * 128 + col4);
            s0 += v.x; s1 += v.y; s2 += v.z; s3 += v.w;
            q0 += v.x * v.x; q1 += v.y * v.y; q2 += v.z * v.z; q3 += v.w * v.w;
        }
        s0 += __shfl_xor(s0, 32); s1 += __shfl_xor(s1, 32);
        s2 += __shfl_xor(s2, 32); s3 += __shfl_xor(s3, 32);
        q0 += __shfl_xor(q0, 32); q1 += __shfl_xor(q1, 32);
        q2 += __shfl_xor(q2, 32); q3 += __shfl_xor(q3, 32);
        __shared__ float red[4][32][8];
        int wv = tid >> 6, l = tid & 63;
        if (l < 32) {
            float* p = red[wv][l];
            p[0] = s0; p[1] = s1; p[2] = s2; p[3] = s3;
            p[4] = q0; p[5] = q1; p[6] = q2; p[7] = q3;
        }
        __syncthreads();
        if (tid < 32) {
            float a0 = 0.f, a1 = 0.f, a2 = 0.f, a3 = 0.f;
            float b0 = 0.f, b1 = 0.f, b2 = 0.f, b3 = 0.f;
#pragma unroll
            for (int w = 0; w < 4; ++w) {
                float* p = red[w][tid];
                a0 += p[0]; a1 += p[1]; a2 += p[2]; a3 += p[3];
                b0 += p[4]; b1 += p[5]; b2 += p[6]; b3 += p[7];
            }
            int c = tid * 4;
            atomicAdd(&sums[c], a0); atomicAdd(&sums[c + 1], a1);
            atomicAdd(&sums[c + 2], a2); atomicAdd(&sums[c + 3], a3);
            atomicAdd(&sums[128 + c], b0); atomicAdd(&sums[128 + c + 1], b1);
            atomicAdd(&sums[128 + c + 2], b2); atomicAdd(&sums[128 + c + 3], b3);
        }
    } else if (bid < 4149) {
        int i = (bid - 1024) * 256 + tid;
        if (i < EE) atomicAdd(&counts[dst[i]], 1);
    } else {
        int i = (bid - 4149) * 256 + tid;
        if (i < 65536) {                       // Wt0 [256][256]
            int c = i >> 8, k = i & 255;
            const float* W = (c < 128) ? Ws0 : Wd0;
            Wt0[c * 256 + k] = f2b(W[k * 128 + (c & 127)]);
        } else if (i < 98304) {                // Wt1 [256][128]
            int j = i - 65536;
            int c = j >> 7, k = j & 127;
            const float* W = (c < 128) ? Ws1 : Wd1;
            Wt1[c * 128 + k] = f2b(W[k * 128 + (c & 127)]);
        } else if (i < 114688) {               // Wo1t [128][128]
            int j = i - 98304;
            int c = j >> 7, k = j & 127;
            Wo1t[c * 128 + k] = f2b(Wo1[k * 128 + c]);
        } else if (i < 131072) {               // Wo2t [128][128]
            int j = i - 114688;
            int c = j >> 7, k = j & 127;
            Wo2t[c * 128 + k] = f2b(Wo2[k * 128 + c]);
        }
    }
}

// ================= K2: scan_reduce(0-48) | finalize_stats(49) =================
__global__ __launch_bounds__(1024) void head2_kernel(const int* __restrict__ counts,
        int* __restrict__ blockSums, float* __restrict__ stats, int n) {
    int bid = blockIdx.x;
    int tid = threadIdx.x;
    if (bid < 49) {
        int i = bid * 1024 + tid;
        int v = (i < n) ? counts[i] : 0;
#pragma unroll
        for (int o = 32; o > 0; o >>= 1) v += __shfl_down(v, o);
        __shared__ int sh[16];
        int lane = tid & 63, wv = tid >> 6;
        if (lane == 0) sh[wv] = v;
        __syncthreads();
        if (tid == 0) {
            int s = 0;
#pragma unroll
            for (int k = 0; k < 16; ++k) s += sh[k];
            blockSums[bid] = s;
        }
    } else {
        if (tid < 128) {
            int c = tid;
            float sum = stats[c], sumsq = stats[128 + c];
            float mu = sum / (float)n;
            float var = (sumsq - sum * sum / (float)n) / (float)(n - 1);
            stats[256 + c] = mu;
            stats[384 + c] = sqrtf(fmaxf(var, 0.f));
        }
    }
}

// ================= K3: build_h(0-3124) | scan_apply(3125-3173) =================
__global__ __launch_bounds__(1024) void head3_kernel(const float* __restrict__ x,
        const float* __restrict__ noise, const int* __restrict__ t,
        const float* __restrict__ sab, const float* __restrict__ somab,
        const float* __restrict__ temb, const float* __restrict__ stats,
        ushort* __restrict__ h,
        const int* __restrict__ counts, const int* __restrict__ blockSums,
        int* __restrict__ indptr, int* __restrict__ cursor, int n) {
    int bid = blockIdx.x;
    int tid = threadIdx.x;
    if (bid < 3125) {
        int wid = bid * 16 + (tid >> 6);
        int lane = tid & 63;
        int tt = t[wid / NPG];
        float s1 = sab[tt], s2v = somab[tt];
        float2 nz = ((const float2*)noise)[(size_t)wid * 64 + lane];
        float s = nz.x + nz.y;
        float sq = nz.x * nz.x + nz.y * nz.y;
#pragma unroll
        for (int o = 1; o < 64; o <<= 1) { s += __shfl_xor(s, o); sq += __shfl_xor(sq, o); }
        float mu = s * (1.f / 128.f);
        float var = sq * (1.f / 128.f) - mu * mu;
        float r = rsqrtf(var + 1e-5f);
        int f0 = 2 * lane, f1 = f0 + 1;
        float y0 = (nz.x - mu) * r * stats[384 + f0] + stats[256 + f0];
        float y1 = (nz.y - mu) * r * stats[384 + f1] + stats[256 + f1];
        float2 xv = ((const float2*)x)[(size_t)wid * 64 + lane];
        float sg0 = (xv.x > 0.f) ? 1.f : ((xv.x < 0.f) ? -1.f : 0.f);
        float sg1 = (xv.y > 0.f) ? 1.f : ((xv.y < 0.f) ? -1.f : 0.f);
        float n0 = sg0 * fabsf(y0);
        float n1 = sg1 * fabsf(y1);
        float xt0 = s1 * xv.x + s2v * n0;
        float xt1 = s1 * xv.y + s2v * n1;
        uint* row = (uint*)(h + (size_t)wid * 256);
        row[lane] = pack2(xt0, xt1);
        float2 te = ((const float2*)(temb + (size_t)tt * 128))[lane];
        row[64 + lane] = pack2(te.x, te.y);
    } else {
        int b = bid - 3125;                 // 0..48
        __shared__ int sOff, sTot;
        if (tid < 64) {
            int v = (tid < 49) ? blockSums[tid] : 0;
            int incl = v;
#pragma unroll
            for (int o = 1; o < 64; o <<= 1) {
                int tv = __shfl_up(incl, o);
                if ((tid & 63) >= o) incl += tv;
            }
            int off = (b == 0) ? 0 : __shfl(incl, b - 1);
            int tot = __shfl(incl, 48);
            if (tid == 0) { sOff = off; sTot = tot; }
        }
        __syncthreads();
        int i = b * 1024 + tid;
        int v = (i < n) ? counts[i] : 0;
        int lane = tid & 63, wv = tid >> 6;
        int incl = v;
#pragma unroll
        for (int o = 1; o < 64; o <<= 1) {
            int tv = __shfl_up(incl, o);
            if (lane >= o) incl += tv;
        }
        __shared__ int wsum[16];
        __shared__ int woff[16];
        if (lane == 63) wsum[wv] = incl;
        __syncthreads();
        if (tid == 0) {
            int s = 0;
#pragma unroll
            for (int k = 0; k < 16; ++k) { woff[k] = s; s += wsum[k]; }
        }
        __syncthreads();
        int ex = incl - v + woff[wv] + sOff;
        if (i < n) { indptr[i] = ex; cursor[i] = ex; }
        if (b == 48 && tid == 0) indptr[n] = sTot;
    }
}

// ================= scatter =================
__global__ __launch_bounds__(1024) void scatter_kernel(const int* __restrict__ src,
        const int* __restrict__ dst, int* __restrict__ cursor,
        int* __restrict__ csr_src, int e) {
    int i = blockIdx.x * 1024 + threadIdx.x;
    if (i < e) {
        int p = atomicAdd(&cursor[dst[i]], 1);
        csr_src[p] = src[i];
    }
}

// ====== bf16 MFMA GEMM: [fs|fd] = A[M,K] @ Wt^T, fs -> fp8, fd -> bf16 ======
template<int K>
__global__ __launch_bounds__(256, 2) void mfma_gemm(const ushort* __restrict__ A,
        const ushort* __restrict__ Wt, uchar* __restrict__ C8,
        ushort* __restrict__ C1, int M) {
    constexpr int NCOL = 256;
    constexpr int NFRAG = 16;
    constexpr int KSTEPS = K / 32;
    __shared__ ushort Bs[32 * NCOL];
    int tid = threadIdx.x;
    int wave = tid >> 6, lane = tid & 63;
    int l15 = lane & 15, g = lane >> 4;
    int rowBase = blockIdx.x * 64 + wave * 16;
    int rc = min(rowBase + l15, M - 1);
    const ushort* Arow = A + (size_t)rc * K + g * 8;

    f32x4 acc[NFRAG] = {};

    for (int ks = 0; ks < KSTEPS; ++ks) {
#pragma unroll
        for (int i = 0; i < 4; ++i) {
            int ch = tid + i * 256;
            int c = ch >> 2, q = ch & 3;
            float4 v = *(const float4*)(Wt + (size_t)c * K + ks * 32 + q * 8);
            int off = c * 64 + ((q * 16) ^ ((c & 7) << 4));
            *(float4*)((char*)Bs + off) = v;
        }
        __syncthreads();
        bf16x8 af = *(const bf16x8*)(Arow + ks * 32);
        int roff = l15 * 64 + ((g * 16) ^ ((l15 & 7) << 4));
#pragma unroll
        for (int n = 0; n < NFRAG; ++n) {
            bf16x8 bf = *(const bf16x8*)((const char*)Bs + n * 1024 + roff);
            acc[n] = __builtin_amdgcn_mfma_f32_16x16x32_bf16(af, bf, acc[n], 0, 0, 0);
        }
        __syncthreads();
    }

#pragma unroll
    for (int n = 0; n < NFRAG; ++n) {
        int col = n * 16 + l15;
#pragma unroll
        for (int j = 0; j < 4; ++j) {
            int row = rowBase + g * 4 + j;
            if (row < M) {
                float v = acc[n][j];
                if (n < 8) C8[(size_t)row * 128 + col] = enc1(v);
                else       C1[(size_t)row * 128 + col - 128] = f2b(v);
            }
        }
    }
}

// ======= GATv2 + gelu + (bf16 residual) + LN; fp8 fs, 8 edges/wave-load =======
// lane = o(3b)|s(3b): o owns edge j+o, s owns dims 16s..16s+15 (head = s>>1)
__global__ __launch_bounds__(256) void gat_ln_kernel(const uchar* __restrict__ fs8,
        const ushort* __restrict__ fd, const float* __restrict__ a,
        const float* __restrict__ bias, const int* __restrict__ indptr,
        const int* __restrict__ csr_src, const ushort* __restrict__ residB,
        const float* __restrict__ g, const float* __restrict__ be,
        ushort* __restrict__ outB, int n) {
    int wid = (blockIdx.x * blockDim.x + threadIdx.x) >> 6;
    int lane = threadIdx.x & 63;
    if (wid >= n) return;
    int o = lane >> 3, s = lane & 7;
    int beg = indptr[wid], cnt = indptr[wid + 1] - beg;
    const int* ip = csr_src + beg;
    const uint4* fs4 = (const uint4*)fs8;

    float fdv[16], av[16];
    {
        uint4 q0 = ((const uint4*)fd)[(size_t)wid * 16 + 2 * s];
        uint4 q1 = ((const uint4*)fd)[(size_t)wid * 16 + 2 * s + 1];
        unpack8(q0, fdv); unpack8(q1, fdv + 8);
        load16f(a + 16 * s, av);
    }

    int ia = (o < cnt) ? ip[o] : 0;
    int ib = (8 + o < cnt) ? ip[8 + o] : 0;
    uint4 vA = fs4[(size_t)ia * 8 + s];
    uint4 vB = fs4[(size_t)ib * 8 + s];

    float den = 0.f;
    float acc[16] = {};
    for (int j = 0; j < cnt; j += 8) {
        uint4 cur = vA; vA = vB;
        int ic = (j + 16 + o < cnt) ? ip[j + 16 + o] : 0;
        vB = fs4[(size_t)ic * 8 + s];
        float c[16];
        dec16(cur, c);
        float p = 0.f;
#pragma unroll
        for (int i = 0; i < 16; ++i) {
            float tv = c[i] + fdv[i];
            tv = (tv > 0.f) ? tv : 0.2f * tv;
            p = fmaf(tv, av[i], p);
        }
        p += __shfl_xor(p, 1);                       // head logit (32 dims)
        float w = (j + o < cnt) ? __expf(p) : 0.f;   // logits O(0.1): no max-sub
        den += w;
#pragma unroll
        for (int i = 0; i < 16; ++i) acc[i] = fmaf(w, c[i], acc[i]);
    }
    // combine octs (each oct processed different edges)
#pragma unroll
    for (int i = 0; i < 16; ++i) {
        acc[i] += __shfl_xor(acc[i], 8);
        acc[i] += __shfl_xor(acc[i], 16);
        acc[i] += __shfl_xor(acc[i], 32);
    }
    den += __shfl_xor(den, 8);
    den += __shfl_xor(den, 16);
    den += __shfl_xor(den, 32);
    float inv = (cnt > 0) ? 1.f / den : 0.f;

    float bi[16];
    load16f(bias + 16 * s, bi);
    float r[16];
#pragma unroll
    for (int i = 0; i < 16; ++i) r[i] = gelu_exact(acc[i] * inv + bi[i]);
    if (residB) {
        uint4 q0 = ((const uint4*)residB)[(size_t)wid * 16 + 2 * s];
        uint4 q1 = ((const uint4*)residB)[(size_t)wid * 16 + 2 * s + 1];
        float rv[16]; unpack8(q0, rv); unpack8(q1, rv + 8);
#pragma unroll
        for (int i = 0; i < 16; ++i) r[i] += rv[i];
    }
    // LayerNorm over 128 dims (s-group of 8 lanes holds full row)
    float ssum = 0.f, ssq = 0.f;
#pragma unroll
    for (int i = 0; i < 16; ++i) { ssum += r[i]; ssq += r[i] * r[i]; }
#pragma unroll
    for (int off = 1; off < 8; off <<= 1) {
        ssum += __shfl_xor(ssum, off); ssq += __shfl_xor(ssq, off);
    }
    float mu = ssum * (1.f / 128.f);
    float var = ssq * (1.f / 128.f) - mu * mu;
    float rstd = rsqrtf(var + 1e-5f);
    float gv[16], bv[16];
    load16f(g + 16 * s, gv);
    load16f(be + 16 * s, bv);
    float o_[16];
#pragma unroll
    for (int i = 0; i < 16; ++i) o_[i] = (r[i] - mu) * rstd * gv[i] + bv[i];
    if (o == 0) {
        uint4 w0, w1;
        w0.x = pack2(o_[0], o_[1]);  w0.y = pack2(o_[2], o_[3]);
        w0.z = pack2(o_[4], o_[5]);  w0.w = pack2(o_[6], o_[7]);
        w1.x = pack2(o_[8], o_[9]);  w1.y = pack2(o_[10], o_[11]);
        w1.z = pack2(o_[12], o_[13]); w1.w = pack2(o_[14], o_[15]);
        ((uint4*)outB)[(size_t)wid * 16 + 2 * s] = w0;
        ((uint4*)outB)[(size_t)wid * 16 + 2 * s + 1] = w1;
    }
}

// ===== fused MLP + loss: out = relu(Q@Wo1+b1)@Wo2+b2; z stays in LDS =====
__global__ __launch_bounds__(256, 2) void mlp_loss_kernel(const ushort* __restrict__ Qb,
        const ushort* __restrict__ Wo1t, const ushort* __restrict__ Wo2t,
        const float* __restrict__ bo1, const float* __restrict__ bo2,
        const float* __restrict__ X, float* __restrict__ lossAcc, int M) {
    __shared__ ushort W1[16384];   // 32KB swizzled
    __shared__ ushort W2[16384];   // 32KB swizzled
    __shared__ ushort Zt[8192];    // 16KB swizzled z-tile [64][128]
    int tid = threadIdx.x;
    int wave = tid >> 6, lane = tid & 63;
    int l15 = lane & 15, g = lane >> 4;
#pragma unroll
    for (int it = 0; it < 8; ++it) {
        int q = (it * 256 + tid) * 16;            // [0, 32768)
        int col = q >> 8, qk = q & 255;
        int srcb = (col << 8) + (qk ^ ((col & 7) << 4));
        *(float4*)((char*)W1 + q) = *(const float4*)((const char*)Wo1t + srcb);
        *(float4*)((char*)W2 + q) = *(const float4*)((const char*)Wo2t + srcb);
    }
    int rowBase = blockIdx.x * 64 + wave * 16;
    int rc = min(rowBase + l15, M - 1);
    const ushort* Arow = Qb + (size_t)rc * 128 + g * 8;
    f32x4 acc1[8] = {};
    __syncthreads();
#pragma unroll
    for (int ks = 0; ks < 4; ++ks) {
        bf16x8 af = *(const bf16x8*)(Arow + ks * 32);
#pragma unroll
        for (int n = 0; n < 8; ++n) {
            int col = n * 16 + l15;
            int boff = (col << 8) + ((ks * 64 + g * 16) ^ ((col & 7) << 4));
            bf16x8 bf = *(const bf16x8*)((const char*)W1 + boff);
            acc1[n] = __builtin_amdgcn_mfma_f32_16x16x32_bf16(af, bf, acc1[n], 0, 0, 0);
        }
    }
    // relu + bias -> swizzled z-tile in LDS
#pragma unroll
    for (int n = 0; n < 8; ++n) {
        int col = n * 16 + l15;
        float bv = bo1[col];
#pragma unroll
        for (int j = 0; j < 4; ++j) {
            int lr = wave * 16 + g * 4 + j;
            float v = fmaxf(acc1[n][j] + bv, 0.f);
            int zoff = (lr << 8) + ((col * 2) ^ ((lr & 7) << 4));
            *(ushort*)((char*)Zt + zoff) = f2b(v);
        }
    }
    __syncthreads();
    f32x4 acc2[8] = {};
    int lr = wave * 16 + l15;
#pragma unroll
    for (int ks = 0; ks < 4; ++ks) {
        int aoff = (lr << 8) + ((ks * 64 + g * 16) ^ ((lr & 7) << 4));
        bf16x8 af = *(const bf16x8*)((const char*)Zt + aoff);
#pragma unroll
        for (int n = 0; n < 8; ++n) {
            int col = n * 16 + l15;
            int boff = (col << 8) + ((ks * 64 + g * 16) ^ ((col & 7) << 4));
            bf16x8 bf = *(const bf16x8*)((const char*)W2 + boff);
            acc2[n] = __builtin_amdgcn_mfma_f32_16x16x32_bf16(af, bf, acc2[n], 0, 0, 0);
        }
    }
    // fused loss epilogue
    float td2 = 0.f, tcl = 0.f;
#pragma unroll
    for (int j = 0; j < 4; ++j) {
        int row = rowBase + g * 4 + j;
        bool rv = row < M;
        float d2 = 0.f, oo = 0.f, xx = 0.f, ox = 0.f;
#pragma unroll
        for (int n = 0; n < 8; ++n) {
            int col = n * 16 + l15;
            float ov = rv ? (acc2[n][j] + bo2[col]) : 0.f;
            float xv = rv ? X[(size_t)row * 128 + col] : 0.f;
            float e = ov - xv;
            d2 += e * e; oo += ov * ov; xx += xv * xv; ox += ov * xv;
        }
#pragma unroll
        for (int off = 1; off < 16; off <<= 1) {
            d2 += __shfl_xor(d2, off); oo += __shfl_xor(oo, off);
            xx += __shfl_xor(xx, off); ox += __shfl_xor(ox, off);
        }
        if (rv) {
            float no = fmaxf(sqrtf(oo), 1e-12f);
            float nx = fmaxf(sqrtf(xx), 1e-12f);
            float cs = 1.f - ox / (no * nx);
            td2 += d2; tcl += cs * cs;
        }
    }
    __shared__ float sd2[16], scl[16];
    if (l15 == 0) { sd2[wave * 4 + g] = td2; scl[wave * 4 + g] = tcl; }
    __syncthreads();
    if (tid == 0) {
        float a2 = 0.f, ac = 0.f;
#pragma unroll
        for (int k2 = 0; k2 < 16; ++k2) { a2 += sd2[k2]; ac += scl[k2]; }
        atomicAdd(&lossAcc[0], a2);
        atomicAdd(&lossAcc[1], ac);
    }
}

__global__ void loss_final2(const float* __restrict__ lossAcc, float* __restrict__ outp, int n) {
    outp[0] = lossAcc[0] / ((float)n * 128.f) + 0.1f * (lossAcc[1] / (float)n);
}

extern "C" void kernel_launch(void* const* d_in, const int* in_sizes, int n_in,
                              void* d_out, int out_size, void* d_ws, size_t ws_size,
                              hipStream_t stream) {
    const int N = NN, E = EE;
    const float* x     = (const float*)d_in[0];
    const float* noise = (const float*)d_in[1];
    const int*   src   = (const int*)d_in[2];
    const int*   dst   = (const int*)d_in[3];
    const int*   t     = (const int*)d_in[4];
    const float* sab   = (const float*)d_in[5];
    const float* somab = (const float*)d_in[6];
    const float* temb  = (const float*)d_in[7];
    const float* Ws0   = (const float*)d_in[8];
    const float* Wd0   = (const float*)d_in[9];
    const float* a0    = (const float*)d_in[10];
    const float* b0    = (const float*)d_in[11];
    const float* g0    = (const float*)d_in[12];
    const float* be0   = (const float*)d_in[13];
    const float* Ws1   = (const float*)d_in[14];
    const float* Wd1   = (const float*)d_in[15];
    const float* a1    = (const float*)d_in[16];
    const float* b1    = (const float*)d_in[17];
    const float* g1    = (const float*)d_in[18];
    const float* be1   = (const float*)d_in[19];
    const float* Wo1   = (const float*)d_in[20];
    const float* bo1   = (const float*)d_in[21];
    const float* Wo2   = (const float*)d_in[22];
    const float* bo2   = (const float*)d_in[23];

    float* ws = (float*)d_ws;
    ushort* hB  = (ushort*)ws;                       // [N][256] bf16
    ushort* Pb  = (ushort*)ws;                       // LN0 bf16 (overwrites hB front half)
    uchar*  fs8 = (uchar*)(ws + (size_t)N * 128);    // fp8 [N][128]
    ushort* fdB = (ushort*)(ws + (size_t)N * 192);   // bf16 [N][128]; later Qb
    ushort* Qb  = fdB;
    float* wtail = ws + (size_t)N * 384;
    ushort* Wt0  = (ushort*)wtail;                   // [256][256]
    ushort* Wt1  = (ushort*)(wtail + 32768);         // [256][128]
    ushort* Wo1t = (ushort*)(wtail + 49152);         // [128][128]
    ushort* Wo2t = (ushort*)(wtail + 57344);         // [128][128]
    float* stats    = wtail + 65536;                 // 512
    float* lossAcc  = stats + 512;                   // 2
    int* counts  = (int*)(lossAcc + 2048);           // N
    int* indptr  = counts + N;                       // N+1
    int* cursor  = indptr + N + 1;                   // N
    int* csr_src = cursor + N;                       // E
    int* blockSums = csr_src + E;                    // 64

    hipMemsetAsync(stats, 0, 514 * sizeof(float), stream);
    hipMemsetAsync(counts, 0, (size_t)N * sizeof(int), stream);

    head1_kernel<<<4661, 256, 0, stream>>>(x, stats, dst, counts,
                                           Ws0, Wd0, Ws1, Wd1, Wo1, Wo2,
                                           Wt0, Wt1, Wo1t, Wo2t);
    head2_kernel<<<50, 1024, 0, stream>>>(counts, blockSums, stats, N);
    head3_kernel<<<3174, 1024, 0, stream>>>(x, noise, t, sab, somab, temb, stats, hB,
                                            counts, blockSums, indptr, cursor, N);
    scatter_kernel<<<(E + 1023) / 1024, 1024, 0, stream>>>(src, dst, cursor, csr_src, E);

    int gemmGrid = (N + 63) / 64;   // 782
    // layer 0
    mfma_gemm<256><<<gemmGrid, 256, 0, stream>>>(hB, Wt0, fs8, fdB, N);
    gat_ln_kernel<<<(N + 3) / 4, 256, 0, stream>>>(fs8, fdB, a0, b0, indptr, csr_src,
                                                   nullptr, g0, be0, Pb, N);
    // layer 1 (residual = Pb)
    mfma_gemm<128><<<gemmGrid, 256, 0, stream>>>(Pb, Wt1, fs8, fdB, N);
    gat_ln_kernel<<<(N + 3) / 4, 256, 0, stream>>>(fs8, fdB, a1, b1, indptr, csr_src,
                                                   Pb, g1, be1, Qb, N);
    // fused MLP + loss
    mlp_loss_kernel<<<gemmGrid, 256, 0, stream>>>(Qb, Wo1t, Wo2t, bo1, bo2, x, lossAcc, N);
    loss_final2<<<1, 1, 0, stream>>>(lossAcc, (float*)d_out, N);
}

// Round 10
// 395.566 us; speedup vs baseline: 1.1667x; 1.1667x over previous
//
#include <hip/hip_runtime.h>
#include <hip/hip_bf16.h>
#include <hip/hip_fp16.h>
#include <math.h>

#define NN 50000
#define EE 800000
#define NPG 5000

typedef short bf16x8 __attribute__((ext_vector_type(8)));
typedef float f32x4 __attribute__((ext_vector_type(4)));

__device__ __forceinline__ float gelu_exact(float v) {
    return 0.5f * v * (1.0f + erff(v * 0.70710678118654752440f));
}

__device__ __forceinline__ ushort f2b(float f) {
    union { float f; uint u; } v; v.f = f;
    uint r = (v.u + 0x7fffu + ((v.u >> 16) & 1)) >> 16;
    return (ushort)r;
}
__device__ __forceinline__ uint pack2(float a, float b) {
    return (uint)f2b(a) | ((uint)f2b(b) << 16);
}
__device__ __forceinline__ float blo(uint u) {
    union { uint u; float f; } v; v.u = u << 16; return v.f;
}
__device__ __forceinline__ float bhi(uint u) {
    union { uint u; float f; } v; v.u = u & 0xffff0000u; return v.f;
}
__device__ __forceinline__ void unpack8(uint4 u, float* f) {
    f[0] = blo(u.x); f[1] = bhi(u.x); f[2] = blo(u.y); f[3] = bhi(u.y);
    f[4] = blo(u.z); f[5] = bhi(u.z); f[6] = blo(u.w); f[7] = bhi(u.w);
}

// ---- fp8 e5m2: top 8 bits of fp16; decode = shift + cvt, encode = cvt + round ----
__device__ __forceinline__ uchar f2e5m2(float v) {
    __half h = __float2half(v);                     // rte
    union { __half h; ushort u; } c; c.h = h;
    return (uchar)((c.u + 0x7fu + ((c.u >> 8) & 1u)) >> 8);
}
__device__ __forceinline__ float e5m2f(uint b) {
    union { ushort u; __half h; } c; c.u = (ushort)(b << 8);
    return __half2float(c.h);
}
__device__ __forceinline__ void dec8(uint2 u, float* f) {
#pragma unroll
    for (int i = 0; i < 2; ++i) {
        uint w = (&u.x)[i];
        f[4 * i]     = e5m2f(w & 0xffu);
        f[4 * i + 1] = e5m2f((w >> 8) & 0xffu);
        f[4 * i + 2] = e5m2f((w >> 16) & 0xffu);
        f[4 * i + 3] = e5m2f((w >> 24) & 0xffu);
    }
}

// ================= K1: colstats(0-1023) | hist(1024-4148) | convert(4149-4660) =================
__global__ __launch_bounds__(256) void head1_kernel(const float* __restrict__ x,
        float* __restrict__ sums, const int* __restrict__ dst, int* __restrict__ counts,
        const float* __restrict__ Ws0, const float* __restrict__ Wd0,
        const float* __restrict__ Ws1, const float* __restrict__ Wd1,
        const float* __restrict__ Wo1, const float* __restrict__ Wo2,
        ushort* __restrict__ Wt0, ushort* __restrict__ Wt1,
        ushort* __restrict__ Wo1t, ushort* __restrict__ Wo2t) {
    int bid = blockIdx.x;
    int tid = threadIdx.x;
    if (bid < 1024) {
        int col4 = (tid & 31) * 4;
        int rowgrp = tid >> 5;
        float s0 = 0.f, s1 = 0.f, s2 = 0.f, s3 = 0.f;
        float q0 = 0.f, q1 = 0.f, q2 = 0.f, q3 = 0.f;
        for (int r = bid * 8 + rowgrp; r < NN; r += 8192) {
            float4 v = *(const float4*)(x + (size_t)r * 128 + col4);
            s0 += v.x; s1 += v.y; s2 += v.z; s3 += v.w;
            q0 += v.x * v.x; q1 += v.y * v.y; q2 += v.z * v.z; q3 += v.w * v.w;
        }
        s0 += __shfl_xor(s0, 32); s1 += __shfl_xor(s1, 32);
        s2 += __shfl_xor(s2, 32); s3 += __shfl_xor(s3, 32);
        q0 += __shfl_xor(q0, 32); q1 += __shfl_xor(q1, 32);
        q2 += __shfl_xor(q2, 32); q3 += __shfl_xor(q3, 32);
        __shared__ float red[4][32][8];
        int wv = tid >> 6, l = tid & 63;
        if (l < 32) {
            float* p = red[wv][l];
            p[0] = s0; p[1] = s1; p[2] = s2; p[3] = s3;
            p[4] = q0; p[5] = q1; p[6] = q2; p[7] = q3;
        }
        __syncthreads();
        if (tid < 32) {
            float a0 = 0.f, a1 = 0.f, a2 = 0.f, a3 = 0.f;
            float b0 = 0.f, b1 = 0.f, b2 = 0.f, b3 = 0.f;
#pragma unroll
            for (int w = 0; w < 4; ++w) {
                float* p = red[w][tid];
                a0 += p[0]; a1 += p[1]; a2 += p[2]; a3 += p[3];
                b0 += p[4]; b1 += p[5]; b2 += p[6]; b3 += p[7];
            }
            int c = tid * 4;
            atomicAdd(&sums[c], a0); atomicAdd(&sums[c + 1], a1);
            atomicAdd(&sums[c + 2], a2); atomicAdd(&sums[c + 3], a3);
            atomicAdd(&sums[128 + c], b0); atomicAdd(&sums[128 + c + 1], b1);
            atomicAdd(&sums[128 + c + 2], b2); atomicAdd(&sums[128 + c + 3], b3);
        }
    } else if (bid < 4149) {
        int i = (bid - 1024) * 256 + tid;
        if (i < EE) atomicAdd(&counts[dst[i]], 1);
    } else {
        int i = (bid - 4149) * 256 + tid;
        if (i < 65536) {                       // Wt0 [256][256]
            int c = i >> 8, k = i & 255;
            const float* W = (c < 128) ? Ws0 : Wd0;
            Wt0[c * 256 + k] = f2b(W[k * 128 + (c & 127)]);
        } else if (i < 98304) {                // Wt1 [256][128]
            int j = i - 65536;
            int c = j >> 7, k = j & 127;
            const float* W = (c < 128) ? Ws1 : Wd1;
            Wt1[c * 128 + k] = f2b(W[k * 128 + (c & 127)]);
        } else if (i < 114688) {               // Wo1t [128][128]
            int j = i - 98304;
            int c = j >> 7, k = j & 127;
            Wo1t[c * 128 + k] = f2b(Wo1[k * 128 + c]);
        } else if (i < 131072) {               // Wo2t [128][128]
            int j = i - 114688;
            int c = j >> 7, k = j & 127;
            Wo2t[c * 128 + k] = f2b(Wo2[k * 128 + c]);
        }
    }
}

// ================= K2: scan_reduce(0-48) | finalize_stats(49) =================
__global__ __launch_bounds__(1024) void head2_kernel(const int* __restrict__ counts,
        int* __restrict__ blockSums, float* __restrict__ stats, int n) {
    int bid = blockIdx.x;
    int tid = threadIdx.x;
    if (bid < 49) {
        int i = bid * 1024 + tid;
        int v = (i < n) ? counts[i] : 0;
#pragma unroll
        for (int o = 32; o > 0; o >>= 1) v += __shfl_down(v, o);
        __shared__ int sh[16];
        int lane = tid & 63, wv = tid >> 6;
        if (lane == 0) sh[wv] = v;
        __syncthreads();
        if (tid == 0) {
            int s = 0;
#pragma unroll
            for (int k = 0; k < 16; ++k) s += sh[k];
            blockSums[bid] = s;
        }
    } else {
        if (tid < 128) {
            int c = tid;
            float sum = stats[c], sumsq = stats[128 + c];
            float mu = sum / (float)n;
            float var = (sumsq - sum * sum / (float)n) / (float)(n - 1);
            stats[256 + c] = mu;
            stats[384 + c] = sqrtf(fmaxf(var, 0.f));
        }
    }
}

// ================= K3: build_h(0-3124) | scan_apply(3125-3173) =================
__global__ __launch_bounds__(1024) void head3_kernel(const float* __restrict__ x,
        const float* __restrict__ noise, const int* __restrict__ t,
        const float* __restrict__ sab, const float* __restrict__ somab,
        const float* __restrict__ temb, const float* __restrict__ stats,
        ushort* __restrict__ h,
        const int* __restrict__ counts, const int* __restrict__ blockSums,
        int* __restrict__ indptr, int* __restrict__ cursor, int n) {
    int bid = blockIdx.x;
    int tid = threadIdx.x;
    if (bid < 3125) {
        int wid = bid * 16 + (tid >> 6);
        int lane = tid & 63;
        int tt = t[wid / NPG];
        float s1 = sab[tt], s2v = somab[tt];
        float2 nz = ((const float2*)noise)[(size_t)wid * 64 + lane];
        float s = nz.x + nz.y;
        float sq = nz.x * nz.x + nz.y * nz.y;
#pragma unroll
        for (int o = 1; o < 64; o <<= 1) { s += __shfl_xor(s, o); sq += __shfl_xor(sq, o); }
        float mu = s * (1.f / 128.f);
        float var = sq * (1.f / 128.f) - mu * mu;
        float r = rsqrtf(var + 1e-5f);
        int f0 = 2 * lane, f1 = f0 + 1;
        float y0 = (nz.x - mu) * r * stats[384 + f0] + stats[256 + f0];
        float y1 = (nz.y - mu) * r * stats[384 + f1] + stats[256 + f1];
        float2 xv = ((const float2*)x)[(size_t)wid * 64 + lane];
        float sg0 = (xv.x > 0.f) ? 1.f : ((xv.x < 0.f) ? -1.f : 0.f);
        float sg1 = (xv.y > 0.f) ? 1.f : ((xv.y < 0.f) ? -1.f : 0.f);
        float n0 = sg0 * fabsf(y0);
        float n1 = sg1 * fabsf(y1);
        float xt0 = s1 * xv.x + s2v * n0;
        float xt1 = s1 * xv.y + s2v * n1;
        uint* row = (uint*)(h + (size_t)wid * 256);
        row[lane] = pack2(xt0, xt1);
        float2 te = ((const float2*)(temb + (size_t)tt * 128))[lane];
        row[64 + lane] = pack2(te.x, te.y);
    } else {
        int b = bid - 3125;                 // 0..48
        __shared__ int sOff, sTot;
        if (tid < 64) {
            int v = (tid < 49) ? blockSums[tid] : 0;
            int incl = v;
#pragma unroll
            for (int o = 1; o < 64; o <<= 1) {
                int tv = __shfl_up(incl, o);
                if ((tid & 63) >= o) incl += tv;
            }
            int off = (b == 0) ? 0 : __shfl(incl, b - 1);
            int tot = __shfl(incl, 48);
            if (tid == 0) { sOff = off; sTot = tot; }
        }
        __syncthreads();
        int i = b * 1024 + tid;
        int v = (i < n) ? counts[i] : 0;
        int lane = tid & 63, wv = tid >> 6;
        int incl = v;
#pragma unroll
        for (int o = 1; o < 64; o <<= 1) {
            int tv = __shfl_up(incl, o);
            if (lane >= o) incl += tv;
        }
        __shared__ int wsum[16];
        __shared__ int woff[16];
        if (lane == 63) wsum[wv] = incl;
        __syncthreads();
        if (tid == 0) {
            int s = 0;
#pragma unroll
            for (int k = 0; k < 16; ++k) { woff[k] = s; s += wsum[k]; }
        }
        __syncthreads();
        int ex = incl - v + woff[wv] + sOff;
        if (i < n) { indptr[i] = ex; cursor[i] = ex; }
        if (b == 48 && tid == 0) indptr[n] = sTot;
    }
}

// ================= scatter =================
__global__ __launch_bounds__(1024) void scatter_kernel(const int* __restrict__ src,
        const int* __restrict__ dst, int* __restrict__ cursor,
        int* __restrict__ csr_src, int e) {
    int i = blockIdx.x * 1024 + threadIdx.x;
    if (i < e) {
        int p = atomicAdd(&cursor[dst[i]], 1);
        csr_src[p] = src[i];
    }
}

// ================= bf16 MFMA GEMM: C[M,NCOL] = A[M,K] @ Wt^T ================
// EPI 0 (NCOL=256): cols 0-127 -> fp8 e5m2 C8 (fs), cols 128-255 -> bf16 C1 (fd).
// EPI 1: bias+relu -> bf16 C1. EPI 3: bias + fused loss vs X -> lossAcc.
template<int K, int NCOL, int EPI>
__global__ __launch_bounds__(256, 2) void mfma_gemm(const ushort* __restrict__ A,
        const ushort* __restrict__ Wt, const float* __restrict__ bias,
        uchar* __restrict__ C8, ushort* __restrict__ C1,
        const float* __restrict__ X, float* __restrict__ lossAcc, int M) {
    constexpr int NFRAG = NCOL / 16;
    constexpr int KSTEPS = K / 32;
    __shared__ ushort Bs[32 * NCOL];     // XOR-swizzled [col][kk]
    int tid = threadIdx.x;
    int wave = tid >> 6, lane = tid & 63;
    int l15 = lane & 15, g = lane >> 4;
    int rowBase = blockIdx.x * 64 + wave * 16;
    int rc = min(rowBase + l15, M - 1);
    const ushort* Arow = A + (size_t)rc * K + g * 8;

    f32x4 acc[NFRAG] = {};

    for (int ks = 0; ks < KSTEPS; ++ks) {
#pragma unroll
        for (int i = 0; i < NCOL / 64; ++i) {
            int ch = tid + i * 256;
            int c = ch >> 2, q = ch & 3;
            float4 v = *(const float4*)(Wt + (size_t)c * K + ks * 32 + q * 8);
            int off = c * 64 + ((q * 16) ^ ((c & 7) << 4));
            *(float4*)((char*)Bs + off) = v;
        }
        __syncthreads();
        bf16x8 af = *(const bf16x8*)(Arow + ks * 32);
        int roff = l15 * 64 + ((g * 16) ^ ((l15 & 7) << 4));
#pragma unroll
        for (int n = 0; n < NFRAG; ++n) {
            bf16x8 bf = *(const bf16x8*)((const char*)Bs + n * 1024 + roff);
            acc[n] = __builtin_amdgcn_mfma_f32_16x16x32_bf16(af, bf, acc[n], 0, 0, 0);
        }
        __syncthreads();
    }

    if (EPI != 3) {
#pragma unroll
        for (int n = 0; n < NFRAG; ++n) {
            int col = n * 16 + l15;
#pragma unroll
            for (int j = 0; j < 4; ++j) {
                int row = rowBase + g * 4 + j;
                if (row < M) {
                    float v = acc[n][j];
                    if (EPI == 1) v = fmaxf(v + bias[col], 0.f);
                    if (NCOL == 256) {
                        if (n < 8) C8[(size_t)row * 128 + col] = f2e5m2(v);
                        else       C1[(size_t)row * 128 + col - 128] = f2b(v);
                    } else {
                        C1[(size_t)row * 128 + col] = f2b(v);
                    }
                }
            }
        }
    } else {
        // fused loss epilogue
        float td2 = 0.f, tcl = 0.f;
#pragma unroll
        for (int j = 0; j < 4; ++j) {
            int row = rowBase + g * 4 + j;
            bool rv = row < M;
            float d2 = 0.f, oo = 0.f, xx = 0.f, ox = 0.f;
#pragma unroll
            for (int n = 0; n < NFRAG; ++n) {
                int col = n * 16 + l15;
                float o = rv ? (acc[n][j] + bias[col]) : 0.f;
                float xv = rv ? X[(size_t)row * 128 + col] : 0.f;
                float e = o - xv;
                d2 += e * e; oo += o * o; xx += xv * xv; ox += o * xv;
            }
#pragma unroll
            for (int off = 1; off < 16; off <<= 1) {
                d2 += __shfl_xor(d2, off); oo += __shfl_xor(oo, off);
                xx += __shfl_xor(xx, off); ox += __shfl_xor(ox, off);
            }
            if (rv) {
                float no = fmaxf(sqrtf(oo), 1e-12f);
                float nx = fmaxf(sqrtf(xx), 1e-12f);
                float cs = 1.f - ox / (no * nx);
                td2 += d2; tcl += cs * cs;
            }
        }
        __shared__ float sd2[16], scl[16];
        if (l15 == 0) { sd2[wave * 4 + g] = td2; scl[wave * 4 + g] = tcl; }
        __syncthreads();
        if (tid == 0) {
            float a2 = 0.f, ac = 0.f;
#pragma unroll
            for (int k2 = 0; k2 < 16; ++k2) { a2 += sd2[k2]; ac += scl[k2]; }
            atomicAdd(&lossAcc[0], a2);
            atomicAdd(&lossAcc[1], ac);
        }
    }
}

// ======= GATv2 + gelu + (bf16 residual) + LN; fp8-e5m2 fs, 4 edges/wave-load =======
// lane = quad(2b) | s(4b): quad owns edge j+quad, s owns dims 8s..8s+7 (head = s>>2)
__global__ __launch_bounds__(256) void gat_ln_kernel(const uchar* __restrict__ fs8,
        const ushort* __restrict__ fd, const float* __restrict__ a,
        const float* __restrict__ bias, const int* __restrict__ indptr,
        const int* __restrict__ csr_src, const ushort* __restrict__ residB,
        const float* __restrict__ g, const float* __restrict__ be,
        ushort* __restrict__ outB, int n) {
    int wid = (blockIdx.x * blockDim.x + threadIdx.x) >> 6;
    int lane = threadIdx.x & 63;
    if (wid >= n) return;
    int quad = lane >> 4, s = lane & 15;
    int beg = indptr[wid], cnt = indptr[wid + 1] - beg;
    const int* ip = csr_src + beg;
    const uint2* fs2 = (const uint2*)fs8;

    uint4 fdq = ((const uint4*)fd)[(size_t)wid * 16 + s];
    float fdv[8]; unpack8(fdq, fdv);
    float av[8];
    {
        float4 a0 = *(const float4*)(a + 8 * s);
        float4 a1 = *(const float4*)(a + 8 * s + 4);
        av[0] = a0.x; av[1] = a0.y; av[2] = a0.z; av[3] = a0.w;
        av[4] = a1.x; av[5] = a1.y; av[6] = a1.z; av[7] = a1.w;
    }

    int i0 = (quad < cnt) ? ip[quad] : 0;
    int i1 = (4 + quad < cnt) ? ip[4 + quad] : 0;
    uint2 vA = fs2[(size_t)i0 * 16 + s];
    uint2 vB = fs2[(size_t)i1 * 16 + s];
    int p0 = (8  < cnt) ? ip[8]  : 0;
    int p1 = (9  < cnt) ? ip[9]  : 0;
    int p2 = (10 < cnt) ? ip[10] : 0;
    int p3 = (11 < cnt) ? ip[11] : 0;

    float den = 0.f;
    float acc[8] = {};
    for (int j = 0; j < cnt; j += 4) {
        uint2 cur = vA; vA = vB;
        int pe = (quad == 0) ? p0 : (quad == 1) ? p1 : (quad == 2) ? p2 : p3;
        vB = fs2[(size_t)pe * 16 + s];
        p0 = (j + 12 < cnt) ? ip[j + 12] : 0;
        p1 = (j + 13 < cnt) ? ip[j + 13] : 0;
        p2 = (j + 14 < cnt) ? ip[j + 14] : 0;
        p3 = (j + 15 < cnt) ? ip[j + 15] : 0;
        float c[8]; dec8(cur, c);
        float p = 0.f;
#pragma unroll
        for (int i = 0; i < 8; ++i) {
            float tv = c[i] + fdv[i];
            tv = (tv > 0.f) ? tv : 0.2f * tv;
            p = fmaf(tv, av[i], p);
        }
        p += __shfl_xor(p, 1);
        p += __shfl_xor(p, 2);          // head total (4-lane group)
        float w = (j + quad < cnt) ? __expf(p) : 0.f;   // logits O(0.1): no max-sub
        den += w;
#pragma unroll
        for (int i = 0; i < 8; ++i) acc[i] = fmaf(w, c[i], acc[i]);
    }
    // combine quads (each processed different edges of this node)
#pragma unroll
    for (int i = 0; i < 8; ++i) {
        acc[i] += __shfl_xor(acc[i], 16);
        acc[i] += __shfl_xor(acc[i], 32);
    }
    den += __shfl_xor(den, 16);
    den += __shfl_xor(den, 32);
    float inv = (cnt > 0) ? 1.f / den : 0.f;

    float bi[8];
    {
        float4 b0v = *(const float4*)(bias + 8 * s);
        float4 b1v = *(const float4*)(bias + 8 * s + 4);
        bi[0] = b0v.x; bi[1] = b0v.y; bi[2] = b0v.z; bi[3] = b0v.w;
        bi[4] = b1v.x; bi[5] = b1v.y; bi[6] = b1v.z; bi[7] = b1v.w;
    }
    float r[8];
#pragma unroll
    for (int i = 0; i < 8; ++i) r[i] = gelu_exact(acc[i] * inv + bi[i]);
    if (residB) {
        uint4 rq = ((const uint4*)residB)[(size_t)wid * 16 + s];
        float rv[8]; unpack8(rq, rv);
#pragma unroll
        for (int i = 0; i < 8; ++i) r[i] += rv[i];
    }
    // LayerNorm over 128 dims (16-lane s-group holds all dims; quads redundant)
    float ssum = 0.f, ssq = 0.f;
#pragma unroll
    for (int i = 0; i < 8; ++i) { ssum += r[i]; ssq += r[i] * r[i]; }
#pragma unroll
    for (int o = 1; o < 16; o <<= 1) { ssum += __shfl_xor(ssum, o); ssq += __shfl_xor(ssq, o); }
    float mu = ssum * (1.f / 128.f);
    float var = ssq * (1.f / 128.f) - mu * mu;
    float rstd = rsqrtf(var + 1e-5f);
    float gv[8], bv[8];
    {
        float4 g0v = *(const float4*)(g + 8 * s);
        float4 g1v = *(const float4*)(g + 8 * s + 4);
        gv[0] = g0v.x; gv[1] = g0v.y; gv[2] = g0v.z; gv[3] = g0v.w;
        gv[4] = g1v.x; gv[5] = g1v.y; gv[6] = g1v.z; gv[7] = g1v.w;
        float4 e0v = *(const float4*)(be + 8 * s);
        float4 e1v = *(const float4*)(be + 8 * s + 4);
        bv[0] = e0v.x; bv[1] = e0v.y; bv[2] = e0v.z; bv[3] = e0v.w;
        bv[4] = e1v.x; bv[5] = e1v.y; bv[6] = e1v.z; bv[7] = e1v.w;
    }
    float o_[8];
#pragma unroll
    for (int i = 0; i < 8; ++i) o_[i] = (r[i] - mu) * rstd * gv[i] + bv[i];
    if (quad == 0) {
        uint4 w4;
        w4.x = pack2(o_[0], o_[1]); w4.y = pack2(o_[2], o_[3]);
        w4.z = pack2(o_[4], o_[5]); w4.w = pack2(o_[6], o_[7]);
        ((uint4*)outB)[(size_t)wid * 16 + s] = w4;
    }
}

// ================= final loss combine =================
__global__ void loss_final2(const float* __restrict__ lossAcc, float* __restrict__ outp, int n) {
    outp[0] = lossAcc[0] / ((float)n * 128.f) + 0.1f * (lossAcc[1] / (float)n);
}

extern "C" void kernel_launch(void* const* d_in, const int* in_sizes, int n_in,
                              void* d_out, int out_size, void* d_ws, size_t ws_size,
                              hipStream_t stream) {
    const int N = NN, E = EE;
    const float* x     = (const float*)d_in[0];
    const float* noise = (const float*)d_in[1];
    const int*   src   = (const int*)d_in[2];
    const int*   dst   = (const int*)d_in[3];
    const int*   t     = (const int*)d_in[4];
    const float* sab   = (const float*)d_in[5];
    const float* somab = (const float*)d_in[6];
    const float* temb  = (const float*)d_in[7];
    const float* Ws0   = (const float*)d_in[8];
    const float* Wd0   = (const float*)d_in[9];
    const float* a0    = (const float*)d_in[10];
    const float* b0    = (const float*)d_in[11];
    const float* g0    = (const float*)d_in[12];
    const float* be0   = (const float*)d_in[13];
    const float* Ws1   = (const float*)d_in[14];
    const float* Wd1   = (const float*)d_in[15];
    const float* a1    = (const float*)d_in[16];
    const float* b1    = (const float*)d_in[17];
    const float* g1    = (const float*)d_in[18];
    const float* be1   = (const float*)d_in[19];
    const float* Wo1   = (const float*)d_in[20];
    const float* bo1   = (const float*)d_in[21];
    const float* Wo2   = (const float*)d_in[22];
    const float* bo2   = (const float*)d_in[23];

    float* ws = (float*)d_ws;
    ushort* hB  = (ushort*)ws;                       // [N][256] bf16
    ushort* Pb  = (ushort*)ws;                       // LN0 bf16 (overwrites hB front half)
    uchar*  fs8 = (uchar*)(ws + (size_t)N * 128);    // fp8 e5m2 [N][128]
    ushort* z   = (ushort*)(ws + (size_t)N * 128);   // MLP mid, reuses fs8 region after gat1
    ushort* fdB = (ushort*)(ws + (size_t)N * 192);   // bf16 [N][128]; later Qb
    ushort* Qb  = fdB;
    float* wtail = ws + (size_t)N * 384;
    ushort* Wt0  = (ushort*)wtail;                   // [256][256]
    ushort* Wt1  = (ushort*)(wtail + 32768);         // [256][128]
    ushort* Wo1t = (ushort*)(wtail + 49152);         // [128][128]
    ushort* Wo2t = (ushort*)(wtail + 57344);         // [128][128]
    float* stats    = wtail + 65536;                 // 512
    float* lossAcc  = stats + 512;                   // 2
    int* counts  = (int*)(lossAcc + 2048);           // N
    int* indptr  = counts + N;                       // N+1
    int* cursor  = indptr + N + 1;                   // N
    int* csr_src = cursor + N;                       // E
    int* blockSums = csr_src + E;                    // 64

    hipMemsetAsync(stats, 0, 514 * sizeof(float), stream);
    hipMemsetAsync(counts, 0, (size_t)N * sizeof(int), stream);

    head1_kernel<<<4661, 256, 0, stream>>>(x, stats, dst, counts,
                                           Ws0, Wd0, Ws1, Wd1, Wo1, Wo2,
                                           Wt0, Wt1, Wo1t, Wo2t);
    head2_kernel<<<50, 1024, 0, stream>>>(counts, blockSums, stats, N);
    head3_kernel<<<3174, 1024, 0, stream>>>(x, noise, t, sab, somab, temb, stats, hB,
                                            counts, blockSums, indptr, cursor, N);
    scatter_kernel<<<(E + 1023) / 1024, 1024, 0, stream>>>(src, dst, cursor, csr_src, E);

    int gemmGrid = (N + 63) / 64;   // 782
    // layer 0: fs(fp8)|fd(bf16) = h @ [Ws0|Wd0]
    mfma_gemm<256, 256, 0><<<gemmGrid, 256, 0, stream>>>(hB, Wt0, nullptr, fs8, fdB,
                                                         nullptr, nullptr, N);
    gat_ln_kernel<<<(N + 3) / 4, 256, 0, stream>>>(fs8, fdB, a0, b0, indptr, csr_src,
                                                   nullptr, g0, be0, Pb, N);
    // layer 1 (residual = Pb)
    mfma_gemm<128, 256, 0><<<gemmGrid, 256, 0, stream>>>(Pb, Wt1, nullptr, fs8, fdB,
                                                         nullptr, nullptr, N);
    gat_ln_kernel<<<(N + 3) / 4, 256, 0, stream>>>(fs8, fdB, a1, b1, indptr, csr_src,
                                                   Pb, g1, be1, Qb, N);
    // MLP head: z = relu(Q@Wo1+b); loss fused into second GEMM
    mfma_gemm<128, 128, 1><<<gemmGrid, 256, 0, stream>>>(Qb, Wo1t, bo1, nullptr, z,
                                                         nullptr, nullptr, N);
    mfma_gemm<128, 128, 3><<<gemmGrid, 256, 0, stream>>>(z, Wo2t, bo2, nullptr, nullptr,
                                                         x, lossAcc, N);
    loss_final2<<<1, 1, 0, stream>>>(lossAcc, (float*)d_out, N);
}